// Round 4
// baseline (303.821 us; speedup 1.0000x reference)
//
#include <hip/hip_runtime.h>

// ---------------------------------------------------------------------------
// SparseGRUBrain: N=70000, H=8, E=1.12M, B=8.
// Prep (per call): memset cnt -> hist(rank) -> scan(rowPtr) -> scatter_conv
//   (streams W fp32, converts to bf16, writes 48B CSR-ordered records + srcCSR,
//    and builds calT transpose).
// Main: one wave per neuron, lane=(s,b)=8x8. Sparse phase: lane s handles edges
//   start+s, +8,... reading ONE contiguous 48B bf16 record per edge. Dense
//   phase: slot-parallel U FMAs, then xor REDUCE-SCATTER (7 shfl/gate) leaves
//   lane (s,b) with element-s results -> 3 transcendentals per lane, scalar tail.
// Workspace (bytes):
//   [0,      280K)  cnt
//   [512K,   +280K) rowPtr (N+1)
//   [1M,     +4.5M) rank
//   [6M,     +2.3M) calT (N x 8 f32)
//   [9M,     +4.5M) srcCSR
//   [14M,    +54M)  recs (E x 48B = 3 x uint4 bf16 weights)
// ---------------------------------------------------------------------------

__device__ __forceinline__ float fast_sigmoid(float x) {
    return 1.0f / (1.0f + __expf(-x));
}
__device__ __forceinline__ float fast_tanh(float x) {
    return 2.0f / (1.0f + __expf(-2.0f * x)) - 1.0f;
}

// fp32 -> bf16 bits, round-to-nearest-even
__device__ __forceinline__ unsigned bfr(float x) {
    unsigned u = __float_as_uint(x);
    return (u + 0x7fffu + ((u >> 16) & 1u)) >> 16;
}
__device__ __forceinline__ uint4 pack8(float4 a, float4 b) {
    uint4 r;
    r.x = bfr(a.x) | (bfr(a.y) << 16);
    r.y = bfr(a.z) | (bfr(a.w) << 16);
    r.z = bfr(b.x) | (bfr(b.y) << 16);
    r.w = bfr(b.z) | (bfr(b.w) << 16);
    return r;
}

// unpack 8 bf16 from uint4, fma into acc[8] with scalar c
#define BFMA(acc, p, c)                                                        \
    {                                                                          \
        acc[0] += __uint_as_float((p).x << 16) * (c);                          \
        acc[1] += __uint_as_float((p).x & 0xffff0000u) * (c);                  \
        acc[2] += __uint_as_float((p).y << 16) * (c);                          \
        acc[3] += __uint_as_float((p).y & 0xffff0000u) * (c);                  \
        acc[4] += __uint_as_float((p).z << 16) * (c);                          \
        acc[5] += __uint_as_float((p).z & 0xffff0000u) * (c);                  \
        acc[6] += __uint_as_float((p).w << 16) * (c);                          \
        acc[7] += __uint_as_float((p).w & 0xffff0000u) * (c);                  \
    }

// cnt[t]++ per edge; atomic return = this edge's rank within its bucket.
__global__ void hist_kernel(const int* __restrict__ tgt, int* __restrict__ cnt,
                            int* __restrict__ rank, int E) {
    int i = blockIdx.x * blockDim.x + threadIdx.x;
    int base = i * 4;
    if (base + 3 < E) {
        int4 t = *(const int4*)(tgt + base);
        int4 r;
        r.x = atomicAdd(&cnt[t.x], 1);
        r.y = atomicAdd(&cnt[t.y], 1);
        r.z = atomicAdd(&cnt[t.z], 1);
        r.w = atomicAdd(&cnt[t.w], 1);
        *(int4*)(rank + base) = r;
    } else {
        for (int k = base; k < E; ++k) rank[k] = atomicAdd(&cnt[tgt[k]], 1);
    }
}

// Single-block exclusive scan of raw counts (no padding).
__global__ void scan_kernel(const int* __restrict__ cnt, int* __restrict__ rowPtr, int N) {
    __shared__ int lds[1024];
    const int t = threadIdx.x;
    const int chunk = ((N + 1023) >> 10 | 3) + 1;  // multiple of 4
    const int s0 = t * chunk;
    const int s1 = min(s0 + chunk, N);
    int sum = 0;
    int i = s0;
    for (; i + 3 < s1; i += 4) {
        int4 v = *(const int4*)(cnt + i);
        sum += v.x + v.y + v.z + v.w;
    }
    for (; i < s1; ++i) sum += cnt[i];
    lds[t] = sum;
    __syncthreads();
    for (int off = 1; off < 1024; off <<= 1) {
        int v = (t >= off) ? lds[t - off] : 0;
        __syncthreads();
        lds[t] += v;
        __syncthreads();
    }
    int prefix = (t == 0) ? 0 : lds[t - 1];
    int total = lds[1023];
    for (i = s0; i < s1; ++i) {
        rowPtr[i] = prefix;
        prefix += cnt[i];
    }
    if (t == 0) rowPtr[N] = total;
}

// Streams W (coalesced), converts to bf16, scatters 48B records into CSR order.
// First blocks also build calT (transpose of calcium).
__global__ __launch_bounds__(256) void scatter_conv(
    const int* __restrict__ src, const int* __restrict__ tgt,
    const int* __restrict__ rank, const int* __restrict__ rowPtr,
    const float* __restrict__ Wz, const float* __restrict__ Wr,
    const float* __restrict__ Wh, const float* __restrict__ cal,
    float* __restrict__ calT, uint4* __restrict__ recs,
    int* __restrict__ srcCSR, int N, int E) {
    int gid = blockIdx.x * 256 + threadIdx.x;
    if (gid < N) {  // calcium transpose duty
        float v[8];
#pragma unroll
        for (int b = 0; b < 8; ++b) v[b] = cal[(size_t)b * N + gid];
        float4* o = (float4*)(calT + (size_t)gid * 8);
        o[0] = make_float4(v[0], v[1], v[2], v[3]);
        o[1] = make_float4(v[4], v[5], v[6], v[7]);
    }
    if (gid < E) {
        int t = tgt[gid];
        int pos = rowPtr[t] + rank[gid];
        const float4* wz4 = (const float4*)(Wz + (size_t)gid * 8);
        const float4* wr4 = (const float4*)(Wr + (size_t)gid * 8);
        const float4* wh4 = (const float4*)(Wh + (size_t)gid * 8);
        uint4 pz = pack8(wz4[0], wz4[1]);
        uint4 pr = pack8(wr4[0], wr4[1]);
        uint4 ph = pack8(wh4[0], wh4[1]);
        uint4* rp = recs + (size_t)pos * 3;
        rp[0] = pz;
        rp[1] = pr;
        rp[2] = ph;
        srcCSR[pos] = src[gid];
    }
}

// xor reduce-scatter over the 8 s-lanes: input v[0..7] partials per lane,
// output = fully-reduced value for element index s (lane bits 3,4,5).
__device__ __forceinline__ float rscatter(float v[8], int lane) {
    const bool s0 = (lane & 8) != 0;
    const bool s1 = (lane & 16) != 0;
    const bool s2 = (lane & 32) != 0;
    float w0, w1, w2, w3, x0, x1;
    { float k = s0 ? v[1] : v[0], g = s0 ? v[0] : v[1]; w0 = k + __shfl_xor(g, 8, 64); }
    { float k = s0 ? v[3] : v[2], g = s0 ? v[2] : v[3]; w1 = k + __shfl_xor(g, 8, 64); }
    { float k = s0 ? v[5] : v[4], g = s0 ? v[4] : v[5]; w2 = k + __shfl_xor(g, 8, 64); }
    { float k = s0 ? v[7] : v[6], g = s0 ? v[6] : v[7]; w3 = k + __shfl_xor(g, 8, 64); }
    { float k = s1 ? w1 : w0, g = s1 ? w0 : w1; x0 = k + __shfl_xor(g, 16, 64); }
    { float k = s1 ? w3 : w2, g = s1 ? w2 : w3; x1 = k + __shfl_xor(g, 16, 64); }
    float k = s2 ? x1 : x0, g = s2 ? x0 : x1;
    return k + __shfl_xor(g, 32, 64);
}

// Main: one wave per neuron. lane = s*8 + b.
__global__ __launch_bounds__(256) void gru_main(
    const float* __restrict__ calT, const float* __restrict__ hidden,
    const uint4* __restrict__ recs, const int* __restrict__ srcCSR,
    const float* __restrict__ Uz, const float* __restrict__ Ur,
    const float* __restrict__ Uh, const float* __restrict__ bz,
    const float* __restrict__ br, const float* __restrict__ bh,
    const float* __restrict__ proj, const int* __restrict__ rowPtr,
    float* __restrict__ outCal, float* __restrict__ outHid, int N) {
    const int lane = threadIdx.x & 63;
    const int n = blockIdx.x * 4 + (threadIdx.x >> 6);
    if (n >= N) return;
    const int s = lane >> 3;  // slot / h-element index
    const int b = lane & 7;   // batch

    const int start = rowPtr[n];
    const int end = rowPtr[n + 1];

    // hoisted scalar hidden element (one per lane)
    const float hvS = hidden[((b * N + n) << 3) + s];

    float az[8] = {0, 0, 0, 0, 0, 0, 0, 0};
    float ar[8] = {0, 0, 0, 0, 0, 0, 0, 0};
    float ah[8] = {0, 0, 0, 0, 0, 0, 0, 0};

    // ---- sparse phase: lane s reads record j = start+s, +8, ... (48B each)
    for (int j = start + s; j < end; j += 8) {
        const uint4* rp = recs + (size_t)j * 3;
        uint4 pz = rp[0];
        uint4 pr = rp[1];
        uint4 ph = rp[2];
        float c = calT[(srcCSR[j] << 3) + b];
        BFMA(az, pz, c);
        BFMA(ar, pr, c);
        BFMA(ah, ph, c);
    }

    // ---- slot-parallel recurrent partials for h = s ----
    const int ub = (n << 6) + (s << 3);
    {
        float4 u0 = *(const float4*)(Uz + ub);
        float4 u1 = *(const float4*)(Uz + ub + 4);
        az[0] += hvS * u0.x; az[1] += hvS * u0.y; az[2] += hvS * u0.z; az[3] += hvS * u0.w;
        az[4] += hvS * u1.x; az[5] += hvS * u1.y; az[6] += hvS * u1.z; az[7] += hvS * u1.w;
    }
    {
        float4 u0 = *(const float4*)(Ur + ub);
        float4 u1 = *(const float4*)(Ur + ub + 4);
        ar[0] += hvS * u0.x; ar[1] += hvS * u0.y; ar[2] += hvS * u0.z; ar[3] += hvS * u0.w;
        ar[4] += hvS * u1.x; ar[5] += hvS * u1.y; ar[6] += hvS * u1.z; ar[7] += hvS * u1.w;
    }

    // ---- reduce-scatter -> element-s scalars ----
    float AZ = rscatter(az, lane);
    float AR = rscatter(ar, lane);
    float z = fast_sigmoid(AZ + bz[(n << 3) + s]);
    float r = fast_sigmoid(AR + br[(n << 3) + s]);
    float rhS = r * hvS;

    {
        float4 u0 = *(const float4*)(Uh + ub);
        float4 u1 = *(const float4*)(Uh + ub + 4);
        ah[0] += rhS * u0.x; ah[1] += rhS * u0.y; ah[2] += rhS * u0.z; ah[3] += rhS * u0.w;
        ah[4] += rhS * u1.x; ah[5] += rhS * u1.y; ah[6] += rhS * u1.z; ah[7] += rhS * u1.w;
    }
    float AH = rscatter(ah, lane);
    float ht = fast_tanh(AH + bh[(n << 3) + s]);
    float hn = (1.0f - z) * hvS + z * ht;

    // ---- projection: butterfly all-reduce over s ----
    float cv = hn * proj[s];
    cv += __shfl_xor(cv, 8, 64);
    cv += __shfl_xor(cv, 16, 64);
    cv += __shfl_xor(cv, 32, 64);

    outHid[((b * N + n) << 3) + s] = hn;
    if (s == 0) outCal[b * N + n] = fmaxf(cv, 0.0f);
}

extern "C" void kernel_launch(void* const* d_in, const int* in_sizes, int n_in,
                              void* d_out, int out_size, void* d_ws, size_t ws_size,
                              hipStream_t stream) {
    const float* calcium = (const float*)d_in[0];
    const float* hidden  = (const float*)d_in[1];
    const int*   src     = (const int*)d_in[2];
    const int*   tgt     = (const int*)d_in[3];
    const float* Wz      = (const float*)d_in[4];
    const float* Wr      = (const float*)d_in[5];
    const float* Wh      = (const float*)d_in[6];
    const float* Uz      = (const float*)d_in[7];
    const float* Ur      = (const float*)d_in[8];
    const float* Uh      = (const float*)d_in[9];
    const float* bz      = (const float*)d_in[10];
    const float* br      = (const float*)d_in[11];
    const float* bh      = (const float*)d_in[12];
    const float* proj    = (const float*)d_in[13];

    const int E = in_sizes[2];
    const int H = in_sizes[13];           // 8
    const int N = in_sizes[10] / H;       // 70000
    (void)n_in; (void)out_size; (void)ws_size;

    float* out = (float*)d_out;
    float* outCal = out;
    float* outHid = out + (size_t)in_sizes[0];

    char* ws = (char*)d_ws;
    int*   cnt    = (int*)ws;
    int*   rowPtr = (int*)(ws + (512 << 10));
    int*   rank   = (int*)(ws + (1 << 20));
    float* calT   = (float*)(ws + (6 << 20));
    int*   srcCSR = (int*)(ws + (9 << 20));
    uint4* recs   = (uint4*)(ws + (14 << 20));

    hipMemsetAsync(cnt, 0, (size_t)N * sizeof(int), stream);
    hist_kernel<<<((E + 3) / 4 + 255) / 256, 256, 0, stream>>>(tgt, cnt, rank, E);
    scan_kernel<<<1, 1024, 0, stream>>>(cnt, rowPtr, N);
    {
        int gmax = max(E, N);
        scatter_conv<<<(gmax + 255) / 256, 256, 0, stream>>>(
            src, tgt, rank, rowPtr, Wz, Wr, Wh, calcium, calT, recs, srcCSR, N, E);
    }
    gru_main<<<(N + 3) / 4, 256, 0, stream>>>(
        calT, hidden, recs, srcCSR, Uz, Ur, Uh, bz, br, bh, proj,
        rowPtr, outCal, outHid, N);
}

// Round 5
// 220.195 us; speedup vs baseline: 1.3798x; 1.3798x over previous
//
#include <hip/hip_runtime.h>

// ---------------------------------------------------------------------------
// SparseGRUBrain: N=70000, H=8, E=1.12M, B=8.
// Pipeline (per call, all on stream):
//   memset(cnt,cursor) -> hist(+calT transpose) -> alloc (block-scan + one
//   global atomic per block; rows placed in arbitrary order) -> scatter_conv
//   (streams W fp32 -> bf16 48B CSR records + srcCSR) -> gru_main.
// Main kernel: one wave per neuron, lane=(s,b)=8x8; sparse phase reads one
// contiguous 48B record per edge; dense phase slot-parallel + xor
// reduce-scatter (7 shfl per gate) -> element-parallel tail.
// Workspace (bytes):
//   [0,      280K)  cnt
//   [448K,   +4)    cursor (zeroed by same memset)
//   [512K,   +280K) rowBeg
//   [1M,     +4.5M) rank
//   [6M,     +2.3M) calT ((N+1) x 8 f32)
//   [9M,     +4.5M) srcCSR
//   [14M,    +54M)  recs (E x 48B bf16 weight records)
// ---------------------------------------------------------------------------

__device__ __forceinline__ float fast_sigmoid(float x) {
    return 1.0f / (1.0f + __expf(-x));
}
__device__ __forceinline__ float fast_tanh(float x) {
    return 2.0f / (1.0f + __expf(-2.0f * x)) - 1.0f;
}

// fp32 -> bf16 bits, round-to-nearest-even
__device__ __forceinline__ unsigned bfr(float x) {
    unsigned u = __float_as_uint(x);
    return (u + 0x7fffu + ((u >> 16) & 1u)) >> 16;
}
__device__ __forceinline__ uint4 pack8(float4 a, float4 b) {
    uint4 r;
    r.x = bfr(a.x) | (bfr(a.y) << 16);
    r.y = bfr(a.z) | (bfr(a.w) << 16);
    r.z = bfr(b.x) | (bfr(b.y) << 16);
    r.w = bfr(b.z) | (bfr(b.w) << 16);
    return r;
}

// unpack 8 bf16 from uint4, fma into acc[8] with scalar c
#define BFMA(acc, p, c)                                                        \
    {                                                                          \
        acc[0] += __uint_as_float((p).x << 16) * (c);                          \
        acc[1] += __uint_as_float((p).x & 0xffff0000u) * (c);                  \
        acc[2] += __uint_as_float((p).y << 16) * (c);                          \
        acc[3] += __uint_as_float((p).y & 0xffff0000u) * (c);                  \
        acc[4] += __uint_as_float((p).z << 16) * (c);                          \
        acc[5] += __uint_as_float((p).z & 0xffff0000u) * (c);                  \
        acc[6] += __uint_as_float((p).w << 16) * (c);                          \
        acc[7] += __uint_as_float((p).w & 0xffff0000u) * (c);                  \
    }

// cnt[t]++ per edge (atomic return = rank within bucket); threads < N also
// build calT (transpose of calcium, row N zeroed).
__global__ void hist_kernel(const int* __restrict__ tgt, int* __restrict__ cnt,
                            int* __restrict__ rank, const float* __restrict__ cal,
                            float* __restrict__ calT, int N, int E) {
    int i = blockIdx.x * blockDim.x + threadIdx.x;
    if (i <= N) {
        float4* o = (float4*)(calT + (size_t)i * 8);
        if (i == N) {
            o[0] = make_float4(0.f, 0.f, 0.f, 0.f);
            o[1] = make_float4(0.f, 0.f, 0.f, 0.f);
        } else {
            float v[8];
#pragma unroll
            for (int b = 0; b < 8; ++b) v[b] = cal[(size_t)b * N + i];
            o[0] = make_float4(v[0], v[1], v[2], v[3]);
            o[1] = make_float4(v[4], v[5], v[6], v[7]);
        }
    }
    int base = i * 4;
    if (base + 3 < E) {
        int4 t = *(const int4*)(tgt + base);
        int4 r;
        r.x = atomicAdd(&cnt[t.x], 1);
        r.y = atomicAdd(&cnt[t.y], 1);
        r.z = atomicAdd(&cnt[t.z], 1);
        r.w = atomicAdd(&cnt[t.w], 1);
        *(int4*)(rank + base) = r;
    } else {
        for (int k = base; k < E; ++k) rank[k] = atomicAdd(&cnt[tgt[k]], 1);
    }
}

// Row allocation without a global scan: block-local exclusive scan of cnt,
// one atomicAdd(cursor, blockTotal) per block. Row order is arbitrary.
__global__ __launch_bounds__(256) void alloc_kernel(const int* __restrict__ cnt,
                                                    int* __restrict__ rowBeg,
                                                    int* __restrict__ cursor, int N) {
    __shared__ int waveSum[4];
    const int n = blockIdx.x * 256 + threadIdx.x;
    const int lane = threadIdx.x & 63;
    const int wid = threadIdx.x >> 6;
    int c = (n < N) ? cnt[n] : 0;
    // intra-wave inclusive scan
    int pre = c;
#pragma unroll
    for (int off = 1; off < 64; off <<= 1) {
        int v = __shfl_up(pre, off, 64);
        if (lane >= off) pre += v;
    }
    if (lane == 63) waveSum[wid] = pre;
    __syncthreads();
    if (threadIdx.x == 0) {
        int s0 = waveSum[0], s1 = waveSum[1], s2 = waveSum[2], s3 = waveSum[3];
        int base = atomicAdd(cursor, s0 + s1 + s2 + s3);
        waveSum[0] = base;
        waveSum[1] = base + s0;
        waveSum[2] = base + s0 + s1;
        waveSum[3] = base + s0 + s1 + s2;
    }
    __syncthreads();
    if (n < N) rowBeg[n] = waveSum[wid] + (pre - c);
}

// Streams W (coalesced), converts to bf16, scatters 48B records to CSR slots.
__global__ __launch_bounds__(256) void scatter_conv(
    const int* __restrict__ src, const int* __restrict__ tgt,
    const int* __restrict__ rank, const int* __restrict__ rowBeg,
    const float* __restrict__ Wz, const float* __restrict__ Wr,
    const float* __restrict__ Wh, uint4* __restrict__ recs,
    int* __restrict__ srcCSR, int E) {
    int gid = blockIdx.x * 256 + threadIdx.x;
    if (gid >= E) return;
    int pos = rowBeg[tgt[gid]] + rank[gid];
    const float4* wz4 = (const float4*)(Wz + (size_t)gid * 8);
    const float4* wr4 = (const float4*)(Wr + (size_t)gid * 8);
    const float4* wh4 = (const float4*)(Wh + (size_t)gid * 8);
    uint4 pz = pack8(wz4[0], wz4[1]);
    uint4 pr = pack8(wr4[0], wr4[1]);
    uint4 ph = pack8(wh4[0], wh4[1]);
    uint4* rp = recs + (size_t)pos * 3;
    rp[0] = pz;
    rp[1] = pr;
    rp[2] = ph;
    srcCSR[pos] = src[gid];
}

// xor reduce-scatter over the 8 s-lanes: input v[0..7] partials per lane,
// output = fully-reduced value for element index s (lane bits 3,4,5).
__device__ __forceinline__ float rscatter(float v[8], int lane) {
    const bool s0 = (lane & 8) != 0;
    const bool s1 = (lane & 16) != 0;
    const bool s2 = (lane & 32) != 0;
    float w0, w1, w2, w3, x0, x1;
    { float k = s0 ? v[1] : v[0], g = s0 ? v[0] : v[1]; w0 = k + __shfl_xor(g, 8, 64); }
    { float k = s0 ? v[3] : v[2], g = s0 ? v[2] : v[3]; w1 = k + __shfl_xor(g, 8, 64); }
    { float k = s0 ? v[5] : v[4], g = s0 ? v[4] : v[5]; w2 = k + __shfl_xor(g, 8, 64); }
    { float k = s0 ? v[7] : v[6], g = s0 ? v[6] : v[7]; w3 = k + __shfl_xor(g, 8, 64); }
    { float k = s1 ? w1 : w0, g = s1 ? w0 : w1; x0 = k + __shfl_xor(g, 16, 64); }
    { float k = s1 ? w3 : w2, g = s1 ? w2 : w3; x1 = k + __shfl_xor(g, 16, 64); }
    float k = s2 ? x1 : x0, g = s2 ? x0 : x1;
    return k + __shfl_xor(g, 32, 64);
}

// Main: one wave per neuron. lane = s*8 + b.
__global__ __launch_bounds__(256) void gru_main(
    const float* __restrict__ calT, const float* __restrict__ hidden,
    const uint4* __restrict__ recs, const int* __restrict__ srcCSR,
    const float* __restrict__ Uz, const float* __restrict__ Ur,
    const float* __restrict__ Uh, const float* __restrict__ bz,
    const float* __restrict__ br, const float* __restrict__ bh,
    const float* __restrict__ proj, const int* __restrict__ rowBeg,
    const int* __restrict__ cnt,
    float* __restrict__ outCal, float* __restrict__ outHid, int N) {
    const int lane = threadIdx.x & 63;
    const int n = blockIdx.x * 4 + (threadIdx.x >> 6);
    if (n >= N) return;
    const int s = lane >> 3;  // slot / h-element index
    const int b = lane & 7;   // batch

    const int start = rowBeg[n];
    const int end = start + cnt[n];

    const float hvS = hidden[((b * N + n) << 3) + s];

    float az[8] = {0, 0, 0, 0, 0, 0, 0, 0};
    float ar[8] = {0, 0, 0, 0, 0, 0, 0, 0};
    float ah[8] = {0, 0, 0, 0, 0, 0, 0, 0};

    // ---- sparse phase: lane s reads record j = start+s, +8, ... (48B each)
    for (int j = start + s; j < end; j += 8) {
        const uint4* rp = recs + (size_t)j * 3;
        uint4 pz = rp[0];
        uint4 pr = rp[1];
        uint4 ph = rp[2];
        float c = calT[(srcCSR[j] << 3) + b];
        BFMA(az, pz, c);
        BFMA(ar, pr, c);
        BFMA(ah, ph, c);
    }

    // ---- slot-parallel recurrent partials for h = s ----
    const int ub = (n << 6) + (s << 3);
    {
        float4 u0 = *(const float4*)(Uz + ub);
        float4 u1 = *(const float4*)(Uz + ub + 4);
        az[0] += hvS * u0.x; az[1] += hvS * u0.y; az[2] += hvS * u0.z; az[3] += hvS * u0.w;
        az[4] += hvS * u1.x; az[5] += hvS * u1.y; az[6] += hvS * u1.z; az[7] += hvS * u1.w;
    }
    {
        float4 u0 = *(const float4*)(Ur + ub);
        float4 u1 = *(const float4*)(Ur + ub + 4);
        ar[0] += hvS * u0.x; ar[1] += hvS * u0.y; ar[2] += hvS * u0.z; ar[3] += hvS * u0.w;
        ar[4] += hvS * u1.x; ar[5] += hvS * u1.y; ar[6] += hvS * u1.z; ar[7] += hvS * u1.w;
    }

    // ---- reduce-scatter -> element-s scalars ----
    float AZ = rscatter(az, lane);
    float AR = rscatter(ar, lane);
    float z = fast_sigmoid(AZ + bz[(n << 3) + s]);
    float r = fast_sigmoid(AR + br[(n << 3) + s]);
    float rhS = r * hvS;

    {
        float4 u0 = *(const float4*)(Uh + ub);
        float4 u1 = *(const float4*)(Uh + ub + 4);
        ah[0] += rhS * u0.x; ah[1] += rhS * u0.y; ah[2] += rhS * u0.z; ah[3] += rhS * u0.w;
        ah[4] += rhS * u1.x; ah[5] += rhS * u1.y; ah[6] += rhS * u1.z; ah[7] += rhS * u1.w;
    }
    float AH = rscatter(ah, lane);
    float ht = fast_tanh(AH + bh[(n << 3) + s]);
    float hn = (1.0f - z) * hvS + z * ht;

    // ---- projection: butterfly all-reduce over s ----
    float cv = hn * proj[s];
    cv += __shfl_xor(cv, 8, 64);
    cv += __shfl_xor(cv, 16, 64);
    cv += __shfl_xor(cv, 32, 64);

    outHid[((b * N + n) << 3) + s] = hn;
    if (s == 0) outCal[b * N + n] = fmaxf(cv, 0.0f);
}

extern "C" void kernel_launch(void* const* d_in, const int* in_sizes, int n_in,
                              void* d_out, int out_size, void* d_ws, size_t ws_size,
                              hipStream_t stream) {
    const float* calcium = (const float*)d_in[0];
    const float* hidden  = (const float*)d_in[1];
    const int*   src     = (const int*)d_in[2];
    const int*   tgt     = (const int*)d_in[3];
    const float* Wz      = (const float*)d_in[4];
    const float* Wr      = (const float*)d_in[5];
    const float* Wh      = (const float*)d_in[6];
    const float* Uz      = (const float*)d_in[7];
    const float* Ur      = (const float*)d_in[8];
    const float* Uh      = (const float*)d_in[9];
    const float* bz      = (const float*)d_in[10];
    const float* br      = (const float*)d_in[11];
    const float* bh      = (const float*)d_in[12];
    const float* proj    = (const float*)d_in[13];

    const int E = in_sizes[2];
    const int H = in_sizes[13];           // 8
    const int N = in_sizes[10] / H;       // 70000
    (void)n_in; (void)out_size; (void)ws_size;

    float* out = (float*)d_out;
    float* outCal = out;
    float* outHid = out + (size_t)in_sizes[0];

    char* ws = (char*)d_ws;
    int*   cnt    = (int*)ws;
    int*   cursor = (int*)(ws + (448 << 10));
    int*   rowBeg = (int*)(ws + (512 << 10));
    int*   rank   = (int*)(ws + (1 << 20));
    float* calT   = (float*)(ws + (6 << 20));
    int*   srcCSR = (int*)(ws + (9 << 20));
    uint4* recs   = (uint4*)(ws + (14 << 20));

    // zero cnt [0,280K) and cursor (at 448K) in one memset
    hipMemsetAsync(ws, 0, (448 << 10) + 4, stream);

    int histThreads = (E + 3) / 4;  // 280000 >= N+1, covers calT duty too
    hist_kernel<<<(histThreads + 255) / 256, 256, 0, stream>>>(
        tgt, cnt, rank, calcium, calT, N, E);
    alloc_kernel<<<(N + 255) / 256, 256, 0, stream>>>(cnt, rowBeg, cursor, N);
    scatter_conv<<<(E + 255) / 256, 256, 0, stream>>>(
        src, tgt, rank, rowBeg, Wz, Wr, Wh, recs, srcCSR, E);
    gru_main<<<(N + 3) / 4, 256, 0, stream>>>(
        calT, hidden, recs, srcCSR, Uz, Ur, Uh, bz, br, bh, proj,
        rowBeg, cnt, outCal, outHid, N);
}

// Round 6
// 201.355 us; speedup vs baseline: 1.5089x; 1.0936x over previous
//
#include <hip/hip_runtime.h>

// ---------------------------------------------------------------------------
// SparseGRUBrain: N=70000, H=8, E=1.12M, B=8.
// Pipeline (per call): memset(cnt,cursor) -> hist(+calT transpose, rank) ->
//   alloc (block scan + one global atomic per block) -> scatter_conv (streams
//   W fp32 -> one 64B-aligned bf16 record per edge {Wz,Wr,Wh,src}) -> gru_main.
// Main kernel: one wave per neuron, lane=(s,b)=8x8; sparse phase reads ONE
// 64B record per edge (full line); dense phase loads hoisted above the loop;
// xor reduce-scatter (7 shfl/gate) -> element-parallel tail.
// Workspace (bytes):
//   [0,      280K)  cnt
//   [448K,   +4)    cursor
//   [512K,   +280K) rowBeg
//   [1M,     +4.5M) rank
//   [6M,     +2.3M) calT ((N+1) x 8 f32)
//   [9M,     +72M)  recs (E x 64B records)
// ---------------------------------------------------------------------------

__device__ __forceinline__ float fast_sigmoid(float x) {
    return 1.0f / (1.0f + __expf(-x));
}
__device__ __forceinline__ float fast_tanh(float x) {
    return 2.0f / (1.0f + __expf(-2.0f * x)) - 1.0f;
}

// fp32 -> bf16 bits, round-to-nearest-even
__device__ __forceinline__ unsigned bfr(float x) {
    unsigned u = __float_as_uint(x);
    return (u + 0x7fffu + ((u >> 16) & 1u)) >> 16;
}
__device__ __forceinline__ uint4 pack8(float4 a, float4 b) {
    uint4 r;
    r.x = bfr(a.x) | (bfr(a.y) << 16);
    r.y = bfr(a.z) | (bfr(a.w) << 16);
    r.z = bfr(b.x) | (bfr(b.y) << 16);
    r.w = bfr(b.z) | (bfr(b.w) << 16);
    return r;
}

// unpack 8 bf16 from uint4, fma into acc[8] with scalar c
#define BFMA(acc, p, c)                                                        \
    {                                                                          \
        acc[0] += __uint_as_float((p).x << 16) * (c);                          \
        acc[1] += __uint_as_float((p).x & 0xffff0000u) * (c);                  \
        acc[2] += __uint_as_float((p).y << 16) * (c);                          \
        acc[3] += __uint_as_float((p).y & 0xffff0000u) * (c);                  \
        acc[4] += __uint_as_float((p).z << 16) * (c);                          \
        acc[5] += __uint_as_float((p).z & 0xffff0000u) * (c);                  \
        acc[6] += __uint_as_float((p).w << 16) * (c);                          \
        acc[7] += __uint_as_float((p).w & 0xffff0000u) * (c);                  \
    }

// cnt[t]++ per edge (atomic return = rank within bucket); threads <= N also
// build calT (transpose of calcium, row N zeroed).
__global__ void hist_kernel(const int* __restrict__ tgt, int* __restrict__ cnt,
                            int* __restrict__ rank, const float* __restrict__ cal,
                            float* __restrict__ calT, int N, int E) {
    int i = blockIdx.x * blockDim.x + threadIdx.x;
    if (i <= N) {
        float4* o = (float4*)(calT + (size_t)i * 8);
        if (i == N) {
            o[0] = make_float4(0.f, 0.f, 0.f, 0.f);
            o[1] = make_float4(0.f, 0.f, 0.f, 0.f);
        } else {
            float v[8];
#pragma unroll
            for (int b = 0; b < 8; ++b) v[b] = cal[(size_t)b * N + i];
            o[0] = make_float4(v[0], v[1], v[2], v[3]);
            o[1] = make_float4(v[4], v[5], v[6], v[7]);
        }
    }
    int base = i * 4;
    if (base + 3 < E) {
        int4 t = *(const int4*)(tgt + base);
        int4 r;
        r.x = atomicAdd(&cnt[t.x], 1);
        r.y = atomicAdd(&cnt[t.y], 1);
        r.z = atomicAdd(&cnt[t.z], 1);
        r.w = atomicAdd(&cnt[t.w], 1);
        *(int4*)(rank + base) = r;
    } else {
        for (int k = base; k < E; ++k) rank[k] = atomicAdd(&cnt[tgt[k]], 1);
    }
}

// Row allocation without a global scan: block-local exclusive scan of cnt,
// one atomicAdd(cursor, blockTotal) per block. Row order is arbitrary.
__global__ __launch_bounds__(256) void alloc_kernel(const int* __restrict__ cnt,
                                                    int* __restrict__ rowBeg,
                                                    int* __restrict__ cursor, int N) {
    __shared__ int waveSum[4];
    const int n = blockIdx.x * 256 + threadIdx.x;
    const int lane = threadIdx.x & 63;
    const int wid = threadIdx.x >> 6;
    int c = (n < N) ? cnt[n] : 0;
    int pre = c;
#pragma unroll
    for (int off = 1; off < 64; off <<= 1) {
        int v = __shfl_up(pre, off, 64);
        if (lane >= off) pre += v;
    }
    if (lane == 63) waveSum[wid] = pre;
    __syncthreads();
    if (threadIdx.x == 0) {
        int s0 = waveSum[0], s1 = waveSum[1], s2 = waveSum[2], s3 = waveSum[3];
        int base = atomicAdd(cursor, s0 + s1 + s2 + s3);
        waveSum[0] = base;
        waveSum[1] = base + s0;
        waveSum[2] = base + s0 + s1;
        waveSum[3] = base + s0 + s1 + s2;
    }
    __syncthreads();
    if (n < N) rowBeg[n] = waveSum[wid] + (pre - c);
}

// Streams W (coalesced), converts to bf16, writes ONE 64B-aligned record per
// edge {Wz, Wr, Wh, src} into its CSR slot. 2 edges per thread for store ILP.
__global__ __launch_bounds__(256) void scatter_conv(
    const int* __restrict__ src, const int* __restrict__ tgt,
    const int* __restrict__ rank, const int* __restrict__ rowBeg,
    const float* __restrict__ Wz, const float* __restrict__ Wr,
    const float* __restrict__ Wh, uint4* __restrict__ recs, int E) {
    int i0 = (blockIdx.x * 256 + threadIdx.x) * 2;
    if (i0 + 1 < E) {
        int2 t2 = *(const int2*)(tgt + i0);
        int2 r2 = *(const int2*)(rank + i0);
        int2 s2 = *(const int2*)(src + i0);
        int posA = rowBeg[t2.x] + r2.x;
        int posB = rowBeg[t2.y] + r2.y;
        const float4* wzA = (const float4*)(Wz + (size_t)i0 * 8);
        const float4* wrA = (const float4*)(Wr + (size_t)i0 * 8);
        const float4* whA = (const float4*)(Wh + (size_t)i0 * 8);
        uint4* rpA = recs + (size_t)posA * 4;
        uint4* rpB = recs + (size_t)posB * 4;
        rpA[0] = pack8(wzA[0], wzA[1]);
        rpA[1] = pack8(wrA[0], wrA[1]);
        rpA[2] = pack8(whA[0], whA[1]);
        rpA[3] = make_uint4((unsigned)s2.x, 0, 0, 0);
        rpB[0] = pack8(wzA[2], wzA[3]);
        rpB[1] = pack8(wrA[2], wrA[3]);
        rpB[2] = pack8(whA[2], whA[3]);
        rpB[3] = make_uint4((unsigned)s2.y, 0, 0, 0);
    } else {
        for (int i = i0; i < E; ++i) {
            int pos = rowBeg[tgt[i]] + rank[i];
            const float4* wz4 = (const float4*)(Wz + (size_t)i * 8);
            const float4* wr4 = (const float4*)(Wr + (size_t)i * 8);
            const float4* wh4 = (const float4*)(Wh + (size_t)i * 8);
            uint4* rp = recs + (size_t)pos * 4;
            rp[0] = pack8(wz4[0], wz4[1]);
            rp[1] = pack8(wr4[0], wr4[1]);
            rp[2] = pack8(wh4[0], wh4[1]);
            rp[3] = make_uint4((unsigned)src[i], 0, 0, 0);
        }
    }
}

// xor reduce-scatter over the 8 s-lanes: input v[0..7] partials per lane,
// output = fully-reduced value for element index s (lane bits 3,4,5).
__device__ __forceinline__ float rscatter(float v[8], int lane) {
    const bool s0 = (lane & 8) != 0;
    const bool s1 = (lane & 16) != 0;
    const bool s2 = (lane & 32) != 0;
    float w0, w1, w2, w3, x0, x1;
    { float k = s0 ? v[1] : v[0], g = s0 ? v[0] : v[1]; w0 = k + __shfl_xor(g, 8, 64); }
    { float k = s0 ? v[3] : v[2], g = s0 ? v[2] : v[3]; w1 = k + __shfl_xor(g, 8, 64); }
    { float k = s0 ? v[5] : v[4], g = s0 ? v[4] : v[5]; w2 = k + __shfl_xor(g, 8, 64); }
    { float k = s0 ? v[7] : v[6], g = s0 ? v[6] : v[7]; w3 = k + __shfl_xor(g, 8, 64); }
    { float k = s1 ? w1 : w0, g = s1 ? w0 : w1; x0 = k + __shfl_xor(g, 16, 64); }
    { float k = s1 ? w3 : w2, g = s1 ? w2 : w3; x1 = k + __shfl_xor(g, 16, 64); }
    float k = s2 ? x1 : x0, g = s2 ? x0 : x1;
    return k + __shfl_xor(g, 32, 64);
}

// Main: one wave per neuron. lane = s*8 + b. Dense-phase loads hoisted above
// the sparse loop so their latency hides under the edge traversal.
__global__ __launch_bounds__(256) void gru_main(
    const float* __restrict__ calT, const float* __restrict__ hidden,
    const uint4* __restrict__ recs,
    const float* __restrict__ Uz, const float* __restrict__ Ur,
    const float* __restrict__ Uh, const float* __restrict__ bz,
    const float* __restrict__ br, const float* __restrict__ bh,
    const float* __restrict__ proj, const int* __restrict__ rowBeg,
    const int* __restrict__ cnt,
    float* __restrict__ outCal, float* __restrict__ outHid, int N) {
    const int lane = threadIdx.x & 63;
    const int n = blockIdx.x * 4 + (threadIdx.x >> 6);
    if (n >= N) return;
    const int s = lane >> 3;  // slot / h-element index
    const int b = lane & 7;   // batch

    const int start = rowBeg[n];
    const int end = start + cnt[n];

    // ---- hoisted dense-phase loads (latency hides under the sparse loop) ----
    const float hvS = hidden[((b * N + n) << 3) + s];
    const int ub = (n << 6) + (s << 3);
    float4 uz0 = *(const float4*)(Uz + ub);
    float4 uz1 = *(const float4*)(Uz + ub + 4);
    float4 ur0 = *(const float4*)(Ur + ub);
    float4 ur1 = *(const float4*)(Ur + ub + 4);
    float4 uh0 = *(const float4*)(Uh + ub);
    float4 uh1 = *(const float4*)(Uh + ub + 4);
    const float bzS = bz[(n << 3) + s];
    const float brS = br[(n << 3) + s];
    const float bhS = bh[(n << 3) + s];
    const float pjS = proj[s];

    float az[8] = {0, 0, 0, 0, 0, 0, 0, 0};
    float ar[8] = {0, 0, 0, 0, 0, 0, 0, 0};
    float ah[8] = {0, 0, 0, 0, 0, 0, 0, 0};

    // ---- sparse phase: lane s reads record j = start+s, +8, ... (64B line)
    for (int j = start + s; j < end; j += 8) {
        const uint4* rp = recs + (size_t)j * 4;
        uint4 pz = rp[0];
        uint4 pr = rp[1];
        uint4 ph = rp[2];
        uint4 sx = rp[3];
        float c = calT[((int)sx.x << 3) + b];
        BFMA(az, pz, c);
        BFMA(ar, pr, c);
        BFMA(ah, ph, c);
    }

    // ---- slot-parallel recurrent partials for h = s ----
    az[0] += hvS * uz0.x; az[1] += hvS * uz0.y; az[2] += hvS * uz0.z; az[3] += hvS * uz0.w;
    az[4] += hvS * uz1.x; az[5] += hvS * uz1.y; az[6] += hvS * uz1.z; az[7] += hvS * uz1.w;
    ar[0] += hvS * ur0.x; ar[1] += hvS * ur0.y; ar[2] += hvS * ur0.z; ar[3] += hvS * ur0.w;
    ar[4] += hvS * ur1.x; ar[5] += hvS * ur1.y; ar[6] += hvS * ur1.z; ar[7] += hvS * ur1.w;

    // ---- reduce-scatter -> element-s scalars ----
    float AZ = rscatter(az, lane);
    float AR = rscatter(ar, lane);
    float z = fast_sigmoid(AZ + bzS);
    float r = fast_sigmoid(AR + brS);
    float rhS = r * hvS;

    ah[0] += rhS * uh0.x; ah[1] += rhS * uh0.y; ah[2] += rhS * uh0.z; ah[3] += rhS * uh0.w;
    ah[4] += rhS * uh1.x; ah[5] += rhS * uh1.y; ah[6] += rhS * uh1.z; ah[7] += rhS * uh1.w;
    float AH = rscatter(ah, lane);
    float ht = fast_tanh(AH + bhS);
    float hn = (1.0f - z) * hvS + z * ht;

    // ---- projection: butterfly all-reduce over s ----
    float cv = hn * pjS;
    cv += __shfl_xor(cv, 8, 64);
    cv += __shfl_xor(cv, 16, 64);
    cv += __shfl_xor(cv, 32, 64);

    outHid[((b * N + n) << 3) + s] = hn;
    if (s == 0) outCal[b * N + n] = fmaxf(cv, 0.0f);
}

extern "C" void kernel_launch(void* const* d_in, const int* in_sizes, int n_in,
                              void* d_out, int out_size, void* d_ws, size_t ws_size,
                              hipStream_t stream) {
    const float* calcium = (const float*)d_in[0];
    const float* hidden  = (const float*)d_in[1];
    const int*   src     = (const int*)d_in[2];
    const int*   tgt     = (const int*)d_in[3];
    const float* Wz      = (const float*)d_in[4];
    const float* Wr      = (const float*)d_in[5];
    const float* Wh      = (const float*)d_in[6];
    const float* Uz      = (const float*)d_in[7];
    const float* Ur      = (const float*)d_in[8];
    const float* Uh      = (const float*)d_in[9];
    const float* bz      = (const float*)d_in[10];
    const float* br      = (const float*)d_in[11];
    const float* bh      = (const float*)d_in[12];
    const float* proj    = (const float*)d_in[13];

    const int E = in_sizes[2];
    const int H = in_sizes[13];           // 8
    const int N = in_sizes[10] / H;       // 70000
    (void)n_in; (void)out_size; (void)ws_size;

    float* out = (float*)d_out;
    float* outCal = out;
    float* outHid = out + (size_t)in_sizes[0];

    char* ws = (char*)d_ws;
    int*   cnt    = (int*)ws;
    int*   cursor = (int*)(ws + (448 << 10));
    int*   rowBeg = (int*)(ws + (512 << 10));
    int*   rank   = (int*)(ws + (1 << 20));
    float* calT   = (float*)(ws + (6 << 20));
    uint4* recs   = (uint4*)(ws + (9 << 20));

    // zero cnt [0,280K) and cursor (at 448K) in one memset
    hipMemsetAsync(ws, 0, (448 << 10) + 4, stream);

    int histThreads = (E + 3) / 4;  // 280000 >= N+1, covers calT duty too
    hist_kernel<<<(histThreads + 255) / 256, 256, 0, stream>>>(
        tgt, cnt, rank, calcium, calT, N, E);
    alloc_kernel<<<(N + 255) / 256, 256, 0, stream>>>(cnt, rowBeg, cursor, N);
    scatter_conv<<<((E + 1) / 2 + 255) / 256, 256, 0, stream>>>(
        src, tgt, rank, rowBeg, Wz, Wr, Wh, recs, E);
    gru_main<<<(N + 3) / 4, 256, 0, stream>>>(
        calT, hidden, recs, Uz, Ur, Uh, bz, br, bh, proj,
        rowBeg, cnt, outCal, outHid, N);
}